// Round 1
// baseline (223.333 us; speedup 1.0000x reference)
//
#include <hip/hip_runtime.h>

// MXFP6 quant-dequant (straight-through forward):
//   per 32-elem block: scale = 2^floor(log2(max(|x|, 1e-8)))
//   q = clip(rne(x/scale * 15), -15, 15); out = (q/15) * scale
//
// Mapping: 1 MX block = 32 consecutive floats = 8 lanes x float4.
// Block absmax via 3x DPP cross-lane max within aligned 8-lane groups
// (VALU pipe only -- no ds_bpermute / lgkmcnt waits).
// floor(log2)/exp2 done exactly by masking the fp32 exponent field.
//
// Persistent grid: 2048 blocks x 256 threads, grid-stride with a 4-wide
// batched unroll so 4 independent global_load_dwordx4 are in flight per
// thread. Nontemporal hints: 268 MB streamed once, zero reuse.

typedef float v4f __attribute__((ext_vector_type(4)));

// max over the 8 lanes sharing this MX block (lanes 8k..8k+7), via DPP.
// Step 1: xor1  == quad_perm [1,0,3,2]  (ctrl 0xB1)
// Step 2: xor2  == quad_perm [2,3,0,1]  (ctrl 0x4E)
// Step 3: after steps 1-2 each lane holds its 4-group max, so the
//         row_half_mirror partner (i -> 7-i within each 8-lane half,
//         ctrl 0x141) lives in the other 4-group => full 8-lane max.
__device__ __forceinline__ float dpp_max8(float a) {
  int ai = __float_as_int(a);
  a = fmaxf(a, __int_as_float(
          __builtin_amdgcn_update_dpp(ai, ai, 0xB1, 0xF, 0xF, false)));
  ai = __float_as_int(a);
  a = fmaxf(a, __int_as_float(
          __builtin_amdgcn_update_dpp(ai, ai, 0x4E, 0xF, 0xF, false)));
  ai = __float_as_int(a);
  a = fmaxf(a, __int_as_float(
          __builtin_amdgcn_update_dpp(ai, ai, 0x141, 0xF, 0xF, false)));
  return a;
}

__device__ __forceinline__ v4f qdq4(v4f v) {
  float a = fmaxf(fmaxf(fabsf(v.x), fabsf(v.y)),
                  fmaxf(fabsf(v.z), fabsf(v.w)));
  a = dpp_max8(a);
  a = fmaxf(a, 1e-8f);

  // scale = 2^floor(log2(a)) == exponent part of a (a is normal, >= 1e-8)
  float scale = __uint_as_float(__float_as_uint(a) & 0x7f800000u);
  float inv = 15.0f / scale;           // exact: 15 / power-of-2
  float rs  = scale * (1.0f / 15.0f);  // <=2 ulp vs ref's (q/15)*scale

  v4f o;
  o.x = fminf(fmaxf(rintf(v.x * inv), -15.0f), 15.0f) * rs;
  o.y = fminf(fmaxf(rintf(v.y * inv), -15.0f), 15.0f) * rs;
  o.z = fminf(fmaxf(rintf(v.z * inv), -15.0f), 15.0f) * rs;
  o.w = fminf(fmaxf(rintf(v.w * inv), -15.0f), 15.0f) * rs;
  return o;
}

__global__ __launch_bounds__(256) void mxfp6_qdq_stream(
    const v4f* __restrict__ x, v4f* __restrict__ out, int n4) {
  const int stride = (int)(gridDim.x * blockDim.x);
  const int tid = (int)(blockIdx.x * blockDim.x + threadIdx.x);

  // Grid-stride, 4 float4 per thread per outer iteration.
  // stride is a multiple of 64, so each 8-lane group always maps to one
  // aligned 32-element MX block and guards cut on whole-group boundaries.
  for (int i0 = tid; i0 < n4; i0 += 4 * stride) {
    const int i1 = i0 + stride;
    const int i2 = i0 + 2 * stride;
    const int i3 = i0 + 3 * stride;

    // Batch the loads: 4 independent dwordx4 in flight before any use.
    v4f v0 = __builtin_nontemporal_load(x + i0);
    v4f v1 = (i1 < n4) ? __builtin_nontemporal_load(x + i1) : v4f{0, 0, 0, 0};
    v4f v2 = (i2 < n4) ? __builtin_nontemporal_load(x + i2) : v4f{0, 0, 0, 0};
    v4f v3 = (i3 < n4) ? __builtin_nontemporal_load(x + i3) : v4f{0, 0, 0, 0};

    v4f o0 = qdq4(v0);
    v4f o1 = qdq4(v1);
    v4f o2 = qdq4(v2);
    v4f o3 = qdq4(v3);

    __builtin_nontemporal_store(o0, out + i0);
    if (i1 < n4) __builtin_nontemporal_store(o1, out + i1);
    if (i2 < n4) __builtin_nontemporal_store(o2, out + i2);
    if (i3 < n4) __builtin_nontemporal_store(o3, out + i3);
  }
}

extern "C" void kernel_launch(void* const* d_in, const int* in_sizes, int n_in,
                              void* d_out, int out_size, void* d_ws, size_t ws_size,
                              hipStream_t stream) {
  const float* x = (const float*)d_in[0];
  float* out = (float*)d_out;
  int n = in_sizes[0];          // 4096*8192, divisible by 32
  int n4 = n / 4;               // float4 count
  int block = 256;
  int maxgrid = (n4 + block - 1) / block;
  int grid = maxgrid < 2048 ? maxgrid : 2048;   // persistent, grid-stride
  mxfp6_qdq_stream<<<grid, block, 0, stream>>>(
      (const v4f*)x, (v4f*)out, n4);
}

// Round 2
// 216.480 us; speedup vs baseline: 1.0317x; 1.0317x over previous
//
#include <hip/hip_runtime.h>

// MXFP6 quant-dequant (straight-through forward):
//   per 32-elem block: scale = 2^floor(log2(max(|x|, 1e-8)))
//   q = clip(rne(x/scale * 15), -15, 15); out = (q/15) * scale
//
// Mapping: 1 MX block = 32 consecutive floats = 8 lanes x float4.
// One float4 per thread, exact-fit grid (no loop, no guard work):
// best-measured structure (R0: 216.8 us vs R1 grid-stride: 223.3 us).
//
// Block absmax via 3x DPP cross-lane max within aligned 8-lane groups
// (VALU pipe only -- no ds_bpermute / lgkmcnt waits).
// floor(log2)/exp2 done exactly by masking the fp32 exponent field.
// Nontemporal hints: 268 MB streamed once, zero reuse.

typedef float v4f __attribute__((ext_vector_type(4)));

// max over the 8 lanes sharing this MX block (lanes 8k..8k+7), via DPP.
// Step 1: xor1 == quad_perm [1,0,3,2]  (ctrl 0xB1)
// Step 2: xor2 == quad_perm [2,3,0,1]  (ctrl 0x4E)
// Step 3: after steps 1-2 each lane holds its 4-group max, so the
//         row_half_mirror partner (i -> 7-i within each 8-lane half,
//         ctrl 0x141) lives in the other 4-group => full 8-lane max.
__device__ __forceinline__ float dpp_max8(float a) {
  int ai = __float_as_int(a);
  a = fmaxf(a, __int_as_float(
          __builtin_amdgcn_update_dpp(ai, ai, 0xB1, 0xF, 0xF, false)));
  ai = __float_as_int(a);
  a = fmaxf(a, __int_as_float(
          __builtin_amdgcn_update_dpp(ai, ai, 0x4E, 0xF, 0xF, false)));
  ai = __float_as_int(a);
  a = fmaxf(a, __int_as_float(
          __builtin_amdgcn_update_dpp(ai, ai, 0x141, 0xF, 0xF, false)));
  return a;
}

__global__ __launch_bounds__(256) void mxfp6_qdq_kernel(
    const v4f* __restrict__ x, v4f* __restrict__ out, int n4) {
  int i = blockIdx.x * blockDim.x + threadIdx.x;
  if (i >= n4) return;   // never taken for our shape (n4 % (256) == 0)

  v4f v = __builtin_nontemporal_load(x + i);

  float a = fmaxf(fmaxf(fabsf(v.x), fabsf(v.y)),
                  fmaxf(fabsf(v.z), fabsf(v.w)));
  a = dpp_max8(a);
  a = fmaxf(a, 1e-8f);

  // scale = 2^floor(log2(a)) == exponent part of a (a is normal, >= 1e-8)
  float scale = __uint_as_float(__float_as_uint(a) & 0x7f800000u);
  float inv = 15.0f / scale;           // exact: 15 / power-of-2
  float rs  = scale * (1.0f / 15.0f);  // <=2 ulp vs ref's (q/15)*scale

  v4f o;
  o.x = fminf(fmaxf(rintf(v.x * inv), -15.0f), 15.0f) * rs;
  o.y = fminf(fmaxf(rintf(v.y * inv), -15.0f), 15.0f) * rs;
  o.z = fminf(fmaxf(rintf(v.z * inv), -15.0f), 15.0f) * rs;
  o.w = fminf(fmaxf(rintf(v.w * inv), -15.0f), 15.0f) * rs;
  __builtin_nontemporal_store(o, out + i);
}

extern "C" void kernel_launch(void* const* d_in, const int* in_sizes, int n_in,
                              void* d_out, int out_size, void* d_ws, size_t ws_size,
                              hipStream_t stream) {
  const float* x = (const float*)d_in[0];
  float* out = (float*)d_out;
  int n = in_sizes[0];          // 4096*8192, divisible by 32
  int n4 = n / 4;               // float4 count
  int block = 256;
  int grid = (n4 + block - 1) / block;   // exact fit: 8192 blocks
  mxfp6_qdq_kernel<<<grid, block, 0, stream>>>(
      (const v4f*)x, (v4f*)out, n4);
}